// Round 1
// baseline (108.445 us; speedup 1.0000x reference)
//
#include <hip/hip_runtime.h>
#include <hip/hip_bf16.h>

#define NNEI 255
#define KD 128

typedef __bf16 bf16_t;
typedef __bf16 bf16x8 __attribute__((ext_vector_type(8)));
typedef __bf16 bf16x4 __attribute__((ext_vector_type(4)));
typedef __bf16 bf16x2 __attribute__((ext_vector_type(2)));
typedef float f32x4 __attribute__((ext_vector_type(4)));

__device__ __forceinline__ float fast_tanh(float x) {
    float e = __expf(2.f * x);
    return 1.f - 2.f / (e + 1.f);   // e=inf -> 1, e=0 -> -1 : no NaN
}

__global__ __launch_bounds__(256, 3)
void raa_kernel(const float* __restrict__ q_x, const float* __restrict__ kv_x,
                const float* __restrict__ Wk, const float* __restrict__ Wq,
                const float* __restrict__ Wv, const float* __restrict__ bias,
                const float* __restrict__ score_w, float* __restrict__ out) {
    // LDS: WkT 32KB + kv chunk 16KB + small buffers ~= 52.8KB -> 3 blocks/CU
    __shared__ __align__(16) unsigned char sWkT[128 * 256]; // bf16 [n][k], XOR-swizzled
    __shared__ __align__(16) unsigned char sKV[64 * 256];   // bf16 [row][k], XOR-swizzled
    __shared__ float sQ[128];
    __shared__ float sQB[128];
    __shared__ float sM[4];
    __shared__ float sL[4];
    __shared__ __align__(16) float sAcc[4][128];
    __shared__ float sXP[128];

    const int bt = blockIdx.x;
    const int tid = threadIdx.x;
    const int lane = tid & 63;
    const int w = tid >> 6;

    // ---- load q row ----
    if (tid < 128) sQ[tid] = q_x[bt * 128 + tid];

    // ---- stage Wk^T (B-operand: B[k][n] = Wk[k][n], stored row n major) as bf16 ----
    {
        int j = tid >> 1;            // output col n
        int i0 = (tid & 1) * 64;     // k half
        for (int s8 = 0; s8 < 8; ++s8) {
            bf16x8 pk;
            #pragma unroll
            for (int u = 0; u < 8; ++u)
                pk[u] = (bf16_t)Wk[(i0 + s8 * 8 + u) * 128 + j];
            unsigned off = (unsigned)(j * 256 + (i0 + s8 * 8) * 2) ^ ((unsigned)(j & 7) << 4);
            *(bf16x8*)(sWkT + off) = pk;
        }
    }
    __syncthreads();

    // ---- qb = q @ Wq + bias  (score_b dropped: softmax-invariant) ----
    if (tid < 128) {
        float a = bias[tid];
        for (int i = 0; i < 128; ++i)
            a = fmaf(sQ[i], Wq[i * 128 + tid], a);
        sQB[tid] = a;
    }
    __syncthreads();

    const int r0 = lane & 15;
    const int g4 = lane >> 4;
    float qb_r[8], sw_r[8];
    #pragma unroll
    for (int jt = 0; jt < 8; ++jt) {
        qb_r[jt] = sQB[jt * 16 + r0];
        sw_r[jt] = score_w[jt * 16 + r0];
    }

    const float4* kv4 = (const float4*)(kv_x + (size_t)bt * NNEI * KD);

    float m_run = -3e38f, l_run = 0.f, acc0 = 0.f, acc1 = 0.f;

    for (int c = 0; c < 4; ++c) {
        // ---- stage 64 neighbor rows, f32 -> bf16, swizzled ----
        #pragma unroll
        for (int q = 0; q < 8; ++q) {
            int idx = tid + 256 * q;          // float4 index within chunk
            int g = c * 2048 + idx;           // float4 index within (b,t) block
            float4 v = make_float4(0.f, 0.f, 0.f, 0.f);
            if (g < NNEI * 32) v = kv4[g];    // n=255 row -> zeros
            bf16x4 pk;
            pk[0] = (bf16_t)v.x; pk[1] = (bf16_t)v.y;
            pk[2] = (bf16_t)v.z; pk[3] = (bf16_t)v.w;
            unsigned a = (unsigned)idx * 8;
            unsigned row = a >> 8;
            unsigned off = a ^ ((row & 7) << 4);
            *(bf16x4*)(sKV + off) = pk;
        }
        __syncthreads();

        // ---- keys tile: 16 rows (this wave) x 128 cols via MFMA 16x16x32 bf16 ----
        f32x4 Ck[8];
        #pragma unroll
        for (int jt = 0; jt < 8; ++jt) Ck[jt] = (f32x4){0.f, 0.f, 0.f, 0.f};
        const int rowA = w * 16 + r0;
        const unsigned swzA = ((unsigned)(rowA & 7) << 4);
        #pragma unroll
        for (int ks = 0; ks < 4; ++ks) {
            bf16x8 af = *(const bf16x8*)(sKV +
                (((unsigned)(rowA * 256 + ks * 64 + g4 * 16)) ^ swzA));
            #pragma unroll
            for (int jt = 0; jt < 8; ++jt) {
                int nr = jt * 16 + r0;
                bf16x8 bfr = *(const bf16x8*)(sWkT +
                    (((unsigned)(nr * 256 + ks * 64 + g4 * 16)) ^ ((unsigned)(nr & 7) << 4)));
                Ck[jt] = __builtin_amdgcn_mfma_f32_16x16x32_bf16(af, bfr, Ck[jt], 0, 0, 0);
            }
        }

        // ---- scores: sum_j tanh(key + qb) * sw ; C layout col=lane&15, row=g4*4+reg ----
        float part[4] = {0.f, 0.f, 0.f, 0.f};
        #pragma unroll
        for (int jt = 0; jt < 8; ++jt) {
            #pragma unroll
            for (int reg = 0; reg < 4; ++reg) {
                float x = Ck[jt][reg] + qb_r[jt];
                part[reg] = fmaf(fast_tanh(x), sw_r[jt], part[reg]);
            }
        }
        #pragma unroll
        for (int off = 1; off < 16; off <<= 1) {
            #pragma unroll
            for (int reg = 0; reg < 4; ++reg)
                part[reg] += __shfl_xor(part[reg], off);
        }
        float sc4[4];
        #pragma unroll
        for (int reg = 0; reg < 4; ++reg) {
            int n = c * 64 + w * 16 + g4 * 4 + reg;
            sc4[reg] = (n < NNEI) ? part[reg] : -1e30f;
        }
        // ---- online softmax update (per wave) ----
        float cm = fmaxf(fmaxf(sc4[0], sc4[1]), fmaxf(sc4[2], sc4[3]));
        cm = fmaxf(cm, __shfl_xor(cm, 16));
        cm = fmaxf(cm, __shfl_xor(cm, 32));
        float mn = fmaxf(m_run, cm);
        float scale = __expf(m_run - mn);
        float p[4];
        #pragma unroll
        for (int reg = 0; reg < 4; ++reg) p[reg] = __expf(sc4[reg] - mn);
        float ps = p[0] + p[1] + p[2] + p[3];
        ps += __shfl_xor(ps, 16);
        ps += __shfl_xor(ps, 32);
        l_run = l_run * scale + ps;
        m_run = mn;
        acc0 *= scale; acc1 *= scale;
        // ---- weighted accumulate of kv rows: acc[2*lane+{0,1}] += p_r * kv[r][col] ----
        #pragma unroll
        for (int r = 0; r < 16; ++r) {
            float pb = __shfl(p[r & 3], (r >> 2) * 16);
            int rowK = w * 16 + r;
            unsigned off = ((unsigned)(rowK * 256 + lane * 4)) ^ ((unsigned)(rowK & 7) << 4);
            bf16x2 kvv = *(const bf16x2*)(sKV + off);
            acc0 = fmaf(pb, (float)kvv[0], acc0);
            acc1 = fmaf(pb, (float)kvv[1], acc1);
        }
        __syncthreads();   // before next chunk overwrites sKV
    }

    // ---- cross-wave flash combine ----
    if (lane == 0) { sM[w] = m_run; sL[w] = l_run; }
    sAcc[w][2 * lane]     = acc0;
    sAcc[w][2 * lane + 1] = acc1;
    __syncthreads();

    if (tid < 128) {
        float M4 = fmaxf(fmaxf(sM[0], sM[1]), fmaxf(sM[2], sM[3]));
        float f0 = __expf(sM[0] - M4), f1 = __expf(sM[1] - M4),
              f2 = __expf(sM[2] - M4), f3 = __expf(sM[3] - M4);
        float L = f0 * sL[0] + f1 * sL[1] + f2 * sL[2] + f3 * sL[3];
        float xp = f0 * sAcc[0][tid] + f1 * sAcc[1][tid]
                 + f2 * sAcc[2][tid] + f3 * sAcc[3][tid];
        sXP[tid] = xp / L;
    }
    __syncthreads();

    // ---- x = (sum_n w_n kv_n) @ Wv  (values matmul folded after the weighted sum) ----
    if (tid < 128) {
        float o = 0.f;
        for (int j = 0; j < 128; ++j)
            o = fmaf(sXP[j], Wv[j * 128 + tid], o);
        out[(size_t)bt * 128 + tid] = o;
    }
}

extern "C" void kernel_launch(void* const* d_in, const int* in_sizes, int n_in,
                              void* d_out, int out_size, void* d_ws, size_t ws_size,
                              hipStream_t stream) {
    const float* q_x     = (const float*)d_in[0];
    const float* kv_x    = (const float*)d_in[1];
    const float* Wk      = (const float*)d_in[2];
    const float* Wq      = (const float*)d_in[3];
    const float* Wv      = (const float*)d_in[4];
    const float* bias    = (const float*)d_in[5];
    const float* score_w = (const float*)d_in[6];
    // score_b (d_in[7]) is softmax-invariant: dropped.
    float* out = (float*)d_out;

    raa_kernel<<<dim3(2048), dim3(256), 0, stream>>>(
        q_x, kv_x, Wk, Wq, Wv, bias, score_w, out);
}